// Round 1
// baseline (65.000 us; speedup 1.0000x reference)
//
#include <hip/hip_runtime.h>

#define NBINS 15

// Main kernel: grid-stride over groups of 4 rows. Each group = 3 float4
// logit loads + 1 int4 label load (fully coalesced, 16B/lane).
// Per-thread register histogram (15 bins x {sum_conf, sum_acc}), then
// wave shuffle-reduce -> LDS block reduce -> global atomicAdd into ws.
__global__ __launch_bounds__(256) void ece_main_kernel(
    const float* __restrict__ logits,
    const int* __restrict__ labels,
    float* __restrict__ ws,          // ws[0..14]=sum_conf, ws[15..29]=sum_acc
    long long ngroups)               // N/4
{
    float cs[NBINS];   // per-bin sum of confidences
    float as_[NBINS];  // per-bin sum of accuracies
#pragma unroll
    for (int b = 0; b < NBINS; ++b) { cs[b] = 0.0f; as_[b] = 0.0f; }

    auto proc = [&](float l0, float l1, float l2, int lab) {
        // argmax with first-occurrence tie-break (matches jnp.argmax)
        float m = l0; int p = 0;
        if (l1 > m) { m = l1; p = 1; }
        if (l2 > m) { m = l2; p = 2; }
        // stable softmax max-prob: conf = exp(m-m)/sum = 1/sum
        float s = __expf(l0 - m) + __expf(l1 - m) + __expf(l2 - m);
        float conf = 1.0f / s;
        float acc = (p == lab) ? 1.0f : 0.0f;
        // equal-width bins (b, b+1]/15; searchsorted(left)-1 == floor(conf*15)
        // except at exact boundaries (measure-zero). conf in (1/3, 1].
        int bin = (int)(conf * 15.0f);
        if (bin > NBINS - 1) bin = NBINS - 1;
#pragma unroll
        for (int b = 0; b < NBINS; ++b) {
            cs[b]  += (bin == b) ? conf : 0.0f;
            as_[b] += (bin == b) ? acc  : 0.0f;
        }
    };

    const float4* __restrict__ L4 = (const float4*)logits;
    const int4*  __restrict__ Lb4 = (const int4*)labels;

    long long tid    = (long long)blockIdx.x * blockDim.x + threadIdx.x;
    long long stride = (long long)gridDim.x * blockDim.x;
    for (long long g = tid; g < ngroups; g += stride) {
        float4 a = L4[3 * g + 0];
        float4 b = L4[3 * g + 1];
        float4 c = L4[3 * g + 2];
        int4 lab = Lb4[g];
        // rows: [a.x a.y a.z] [a.w b.x b.y] [b.z b.w c.x] [c.y c.z c.w]
        proc(a.x, a.y, a.z, lab.x);
        proc(a.w, b.x, b.y, lab.y);
        proc(b.z, b.w, c.x, lab.z);
        proc(c.y, c.z, c.w, lab.w);
    }

    // wave (64-lane) shuffle reduction
#pragma unroll
    for (int b = 0; b < NBINS; ++b) {
#pragma unroll
        for (int off = 32; off > 0; off >>= 1) {
            cs[b]  += __shfl_down(cs[b],  off, 64);
            as_[b] += __shfl_down(as_[b], off, 64);
        }
    }

    __shared__ float sred[4][2 * NBINS];  // 4 waves per 256-thread block
    int wave = threadIdx.x >> 6;
    int lane = threadIdx.x & 63;
    if (lane == 0) {
#pragma unroll
        for (int b = 0; b < NBINS; ++b) {
            sred[wave][b]         = cs[b];
            sred[wave][NBINS + b] = as_[b];
        }
    }
    __syncthreads();
    if (threadIdx.x < 2 * NBINS) {
        float v = sred[0][threadIdx.x] + sred[1][threadIdx.x] +
                  sred[2][threadIdx.x] + sred[3][threadIdx.x];
        atomicAdd(&ws[threadIdx.x], v);
    }
}

// Final pass: ece = sum_b |sum_conf_b - sum_acc_b| / N
__global__ void ece_final_kernel(const float* __restrict__ ws,
                                 float* __restrict__ out, float invN) {
    if (threadIdx.x == 0 && blockIdx.x == 0) {
        float e = 0.0f;
#pragma unroll
        for (int b = 0; b < NBINS; ++b)
            e += fabsf(ws[b] - ws[NBINS + b]);
        out[0] = e * invN;
    }
}

extern "C" void kernel_launch(void* const* d_in, const int* in_sizes, int n_in,
                              void* d_out, int out_size, void* d_ws, size_t ws_size,
                              hipStream_t stream) {
    const float* logits = (const float*)d_in[0];
    const int*   labels = (const int*)d_in[1];
    float* out = (float*)d_out;
    float* ws  = (float*)d_ws;

    long long N = in_sizes[1];        // labels count = row count
    long long ngroups = N / 4;        // N = 16777216, divisible by 4

    // zero the 30-float accumulator area every call (deterministic; harness
    // does not re-poison between replays)
    hipMemsetAsync(ws, 0, 2 * NBINS * sizeof(float), stream);

    int block = 256;
    int grid = 2048;  // ~8 groups/thread grid-stride; saturates 256 CUs
    ece_main_kernel<<<grid, block, 0, stream>>>(logits, labels, ws, ngroups);
    ece_final_kernel<<<1, 64, 0, stream>>>(ws, out, 1.0f / (float)N);
}

// Round 2
// 52.061 us; speedup vs baseline: 1.2485x; 1.2485x over previous
//
#include <hip/hip_runtime.h>

#define NBINS 15
#define RB 11            // reachable bins: conf in [1/3-eps, 1] -> bins 4..14
#define BIN_LO 4
#define GRID 2048
#define BLOCK 256

// Accumulate d[b] = sum over elements in bin b of (conf - acc).
// ECE = sum_b |d[b]| / N  (identical to |sum_conf - sum_acc| per bin).
__device__ __forceinline__ void proc_row(float l0, float l1, float l2, int lab,
                                         float* d) {
    // argmax, first-occurrence tie-break (matches jnp.argmax)
    float m = l0; int p = 0;
    if (l1 > m) { m = l1; p = 1; }
    if (l2 > m) { m = l2; p = 2; }
    // conf = max softmax prob = 1 / sum(exp(l - m))
    float s = __expf(l0 - m) + __expf(l1 - m) + __expf(l2 - m);
    float conf = __builtin_amdgcn_rcpf(s);   // v_rcp_f32, ~1ulp, plenty
    // bin = floor(conf*15), clamped; reachable range [4,14] -> idx [0,10]
    int bin = (int)(conf * 15.0f);
    int idx = bin - BIN_LO;
    idx = idx < 0 ? 0 : (idx > RB - 1 ? RB - 1 : idx);
    float x = (p == lab) ? conf - 1.0f : conf;   // conf - accuracy
#pragma unroll
    for (int b = 0; b < RB; ++b)
        d[b] += (idx == b) ? x : 0.0f;
}

__global__ __launch_bounds__(BLOCK) void ece_main(
    const float* __restrict__ logits,
    const int* __restrict__ labels,
    float* __restrict__ part,      // [RB][gridDim.x] partial sums (or atomics)
    long long ngroups, long long nrows, int use_atomic)
{
    float d[RB];
#pragma unroll
    for (int b = 0; b < RB; ++b) d[b] = 0.0f;

    const float4* __restrict__ L4  = (const float4*)logits;
    const int4*  __restrict__  Lb4 = (const int4*)labels;

    long long tid    = (long long)blockIdx.x * blockDim.x + threadIdx.x;
    long long stride = (long long)gridDim.x * blockDim.x;
#pragma unroll 2
    for (long long g = tid; g < ngroups; g += stride) {
        float4 a = L4[3 * g + 0];
        float4 b = L4[3 * g + 1];
        float4 c = L4[3 * g + 2];
        int4 lb  = Lb4[g];
        proc_row(a.x, a.y, a.z, lb.x, d);
        proc_row(a.w, b.x, b.y, lb.y, d);
        proc_row(b.z, b.w, c.x, lb.z, d);
        proc_row(c.y, c.z, c.w, lb.w, d);
    }
    // remainder rows (N not divisible by 4) — handled by one thread
    if (tid == 0) {
        for (long long r = ngroups * 4; r < nrows; ++r)
            proc_row(logits[3 * r], logits[3 * r + 1], logits[3 * r + 2],
                     labels[r], d);
    }

    // 64-lane shuffle reduction
#pragma unroll
    for (int b = 0; b < RB; ++b)
#pragma unroll
        for (int off = 32; off > 0; off >>= 1)
            d[b] += __shfl_down(d[b], off, 64);

    __shared__ float sred[BLOCK / 64][RB];
    int wave = threadIdx.x >> 6, lane = threadIdx.x & 63;
    if (lane == 0)
#pragma unroll
        for (int b = 0; b < RB; ++b) sred[wave][b] = d[b];
    __syncthreads();
    if (threadIdx.x < RB) {
        float v = sred[0][threadIdx.x] + sred[1][threadIdx.x] +
                  sred[2][threadIdx.x] + sred[3][threadIdx.x];
        if (use_atomic)
            atomicAdd(&part[threadIdx.x], v);
        else
            part[(long long)threadIdx.x * gridDim.x + blockIdx.x] = v;
    }
}

__global__ __launch_bounds__(BLOCK) void ece_final(
    const float* __restrict__ part, float* __restrict__ out,
    float invN, int grid, int use_atomic)
{
    if (use_atomic) {
        if (threadIdx.x == 0) {
            float e = 0.0f;
#pragma unroll
            for (int b = 0; b < RB; ++b) e += fabsf(part[b]);
            out[0] = e * invN;
        }
        return;
    }
    float v[RB];
#pragma unroll
    for (int b = 0; b < RB; ++b) v[b] = 0.0f;
    for (int i = threadIdx.x; i < grid; i += BLOCK) {
#pragma unroll
        for (int b = 0; b < RB; ++b) v[b] += part[(long long)b * grid + i];
    }
#pragma unroll
    for (int b = 0; b < RB; ++b)
#pragma unroll
        for (int off = 32; off > 0; off >>= 1)
            v[b] += __shfl_down(v[b], off, 64);
    __shared__ float sred[BLOCK / 64][RB];
    int wave = threadIdx.x >> 6, lane = threadIdx.x & 63;
    if (lane == 0)
#pragma unroll
        for (int b = 0; b < RB; ++b) sred[wave][b] = v[b];
    __syncthreads();
    if (threadIdx.x == 0) {
        float e = 0.0f;
#pragma unroll
        for (int b = 0; b < RB; ++b)
            e += fabsf(sred[0][b] + sred[1][b] + sred[2][b] + sred[3][b]);
        out[0] = e * invN;
    }
}

extern "C" void kernel_launch(void* const* d_in, const int* in_sizes, int n_in,
                              void* d_out, int out_size, void* d_ws, size_t ws_size,
                              hipStream_t stream) {
    const float* logits = (const float*)d_in[0];
    const int*   labels = (const int*)d_in[1];
    float* out  = (float*)d_out;
    float* ws   = (float*)d_ws;

    long long N = in_sizes[1];          // labels count = row count
    long long ngroups = N / 4;

    size_t need = (size_t)RB * GRID * sizeof(float);
    int use_atomic = (ws_size < need) ? 1 : 0;

    if (use_atomic)  // fallback path only: zero the 11-float accumulator
        hipMemsetAsync(ws, 0, RB * sizeof(float), stream);

    ece_main<<<GRID, BLOCK, 0, stream>>>(logits, labels, ws, ngroups, N,
                                         use_atomic);
    ece_final<<<1, BLOCK, 0, stream>>>(ws, out, 1.0f / (float)N, GRID,
                                       use_atomic);
}